// Round 8
// baseline (37649.008 us; speedup 1.0000x reference)
//
#include <hip/hip_runtime.h>
#include <hip/hip_fp16.h>
#include <stdint.h>

// Problem dims
#define B_    64
#define T_    2048
#define IN_   64
#define H_    512
#define H2_   1024
#define OUT_  32
#define KTOT  576          // IN_ + H_

// Grid: 512 blocks = 16 batch-groups x 32 col-groups, 256 threads, 2 blocks/CU.
// bg = blockIdx>>5 so co-resident pairs (i, i+256) are DIFFERENT bgs ->
// independent sync domains anti-phase on one CU (TLP hides MALL RTs).
// VGPR <= 256 is CORRECTNESS (512 blocks must all be resident or the grid
// barrier deadlocks) -> __launch_bounds__(256, 2). Round-5 lesson: weight
// working set must stay in registers; at 4 batches it is ~116 floats.
#define NBG   16
#define NCG   32           // col-groups per bg (barrier fan-in, unchanged)
#define NTHR  256
#define BPG   4            // batches per group
#define KSL   18           // k per slice (32 slices x 18 = 576)
#define RS    12           // bufA row stride in floats (48B, 16B-aligned)

// ws layout (32-bit words)
// Counters: one u32 per (bg, phase), 4KB-strided (round-4 win). 32 counters.
// Slabs fp16: word = (bg*512 + col)*2 + pr, pr = batch-pair (b0=2pr, b1=2pr+1).
#define ABORT_IDX   0
#define CTR_OFF     1024
#define CTR_STRIDE  1024
#define NCTR        (NBG * 2)                       // 32
#define BUF_BASE    (CTR_OFF + NCTR * CTR_STRIDE)   // 33792
#define XSLABW      (NBG * H_ * 2)                  // 16384 words per slab

// ---- fp16 pack/unpack ----
__device__ __forceinline__ unsigned f2h2(float a, float b) {
  __half2 h = __floats2half2_rn(a, b);   // lo = a, hi = b
  unsigned r; __builtin_memcpy(&r, &h, 4); return r;
}
__device__ __forceinline__ float2 h2f2(unsigned u) {
  __half2 h; __builtin_memcpy(&h, &u, 4);
  return __half22float2(h);              // x = lo, y = hi
}

// ---- MALL-resident exchange primitives ----
// Publish packed fp16 pair: fire-and-forget 4B swap at the MALL (sc1).
// The drain (vmcnt 0) is issued explicitly later, after LDS-only work,
// and ALWAYS before the counter bump (round-6 lesson: nothing with VMEM
// between publish and bump; independent VMEM work goes after the bump).
__device__ __forceinline__ void gpubh_nd(unsigned* p, unsigned v) {
  asm volatile("global_atomic_swap %0, %1, off sc1"
               :: "v"(p), "v"(v) : "memory");
}
// Counter bump: fire-and-forget one-way add at the MALL.
__device__ __forceinline__ void gaddu(unsigned* p, unsigned v) {
  asm volatile("global_atomic_add %0, %1, off sc1"
               :: "v"(p), "v"(v) : "memory");
}
// Coherent 4B poll load (bypasses stale L1/L2, reads the MALL).
__device__ __forceinline__ unsigned gpollu(const unsigned* p) {
  unsigned v;
  asm volatile("global_load_dword %0, %1, off sc0 sc1\n\ts_waitcnt vmcnt(0)"
               : "=v"(v) : "v"(p) : "memory");
  return v;
}
// Consume: one MALL-coherent 16B load = 2 cols x 4 batches fp16.
__device__ __forceinline__ void gload1(const unsigned* p0, uint4& a) {
  asm volatile("global_load_dwordx4 %0, %1, off sc0 sc1\n\ts_waitcnt vmcnt(0)"
               : "=&v"(a) : "v"(p0) : "memory");
}

__global__ __launch_bounds__(256) void gru_init(float* ws, const float* __restrict__ x0) {
  int i = blockIdx.x * blockDim.x + threadIdx.x;
  int stride = gridDim.x * blockDim.x;
  unsigned* w = (unsigned*)ws;
  for (int k = i; k < BUF_BASE; k += stride) w[k] = 0u;   // abort + counters
  // xg0 slab (fp16): word p = (bg*512 + col)*2 + pr
  unsigned* xh = w + BUF_BASE;
  for (int p = i; p < XSLABW; p += stride) {
    int bg = p >> 10, col = (p >> 1) & (H_ - 1), pr = p & 1;
    int b0 = bg * BPG + 2 * pr;
    xh[p] = f2h2(x0[b0 * H_ + col], x0[(b0 + 1) * H_ + col]);
  }
}

// Wait: ONE lane polls ONE 4KB-isolated counter word until it reaches target.
__device__ __forceinline__ bool gbar_wait(unsigned* ctr, unsigned target,
                                          unsigned* abort_w) {
  __shared__ int s_ok;
  if (threadIdx.x == 0) {
    int ok = 1;
    int polls = 0;
    while (gpollu(ctr) < target) {
      __builtin_amdgcn_s_sleep(1);
      if ((++polls & 255) == 0) {
        if (__hip_atomic_load(abort_w, __ATOMIC_RELAXED, __HIP_MEMORY_SCOPE_AGENT) != 0u ||
            polls > 2000000) {
          __hip_atomic_store(abort_w, 1u, __ATOMIC_RELAXED, __HIP_MEMORY_SCOPE_AGENT);
          ok = 0;
          break;
        }
      }
    }
    s_ok = ok;
  }
  __syncthreads();
  __atomic_signal_fence(__ATOMIC_ACQUIRE);  // compiler reordering guard only
  return s_ok != 0;
}

__global__ __launch_bounds__(NTHR, 2) void gru_main(
    const float* __restrict__ u, const float* __restrict__ kfz,
    const float* __restrict__ bfz, const float* __restrict__ kr,
    const float* __restrict__ br, const float* __restrict__ wout,
    const float* __restrict__ bout, float* __restrict__ out, float* ws) {
  unsigned* wsu = (unsigned*)ws;
  unsigned* abort_w = wsu + ABORT_IDX;
  unsigned* xg0 = wsu + BUF_BASE;
  unsigned* xg1 = xg0 + XSLABW;
  unsigned* xfg = xg1 + XSLABW;

  const int bg  = blockIdx.x >> 5;   // batch group 0..15 (4 batches each)
  const int cg  = blockIdx.x & 31;   // column group 0..31
  const int tid = threadIdx.x;
  const int w   = tid >> 6;          // wave 0..3
  const int l   = tid & 63;
  const int cq  = l & 7;             // col-quad 0..7
  const int g   = l >> 3;            // in-wave k-slice 0..7
  const int kb  = (w * 8 + g) * KSL; // this thread's k base (18 k's)
  const int fcA = (tid >> 2) & 31;   // finalize-A col 0..31 (valid tid<128)
  const int fb  = tid & 3;           // finalize batch 0..3
  const int fcB = (tid >> 2) & 15;   // finalize-B col 0..15 (valid tid<64)

  unsigned* ctrA = wsu + CTR_OFF + (bg * 2 + 0) * CTR_STRIDE;
  unsigned* ctrB = wsu + CTR_OFF + (bg * 2 + 1) * CTR_STRIDE;

  __shared__ float bufA[KTOT * RS];  // [k][12]: u_t(k<64) | x or f*x (4 b)
  __shared__ float pA[4 * 32 * RS];
  __shared__ float pB[4 * 16 * RS];
  __shared__ float rbuf[16 * 4];

  // ---- one-time: weights into registers (~116 floats/thread) ----
  float wA[KSL][4];
#pragma unroll
  for (int i = 0; i < KSL; ++i)
#pragma unroll
    for (int m = 0; m < 4; ++m) {
      int c = 4 * cq + m;
      int gcol = (c < 16) ? (16 * cg + c) : (512 + 16 * cg + (c - 16));
      wA[i][m] = kfz[(size_t)(kb + i) * H2_ + gcol];
    }
  float wB[KSL][2];
#pragma unroll
  for (int i = 0; i < KSL; ++i)
#pragma unroll
    for (int m = 0; m < 2; ++m)
      wB[i][m] = kr[(size_t)(kb + i) * H_ + (16 * cg + 2 * cq + m)];
  float wy[8];                        // y: wave w = batch w, lane l = k-slice
#pragma unroll
  for (int i = 0; i < 8; ++i) wy[i] = wout[cg * H_ + (l + 64 * i)];
  const float by = bout[cg];
  const int fzc = (fcA < 16) ? (16 * cg + fcA) : (512 + 16 * cg + (fcA - 16));
  const float biasA = bfz[fzc];                  // index always in-bounds
  const float biasB = br[16 * cg + fcB];

  float zreg = 0.0f, xoldz = 0.0f;

  // u_t=0 into LDS rows 0..63 (later steps prefetched after bump-B)
  {
    int k = tid & 63, b = tid >> 6;
    bufA[k * RS + b] = u[((size_t)(bg * BPG + b) * T_) * IN_ + k];
  }

  for (int t = 0; t < T_; ++t) {
    unsigned* xcur = (t & 1) ? xg1 : xg0;
    unsigned* xnxt = (t & 1) ? xg0 : xg1;

    // ---- stage x into bufA: 1 dwordx4 = 2 cols x 4 batches ----
    {
      uint4 a;
      gload1(xcur + (size_t)bg * (H_ * 2) + tid * 4, a);
      float2 c0 = h2f2(a.x), c1 = h2f2(a.y), c2 = h2f2(a.z), c3 = h2f2(a.w);
      *(float4*)&bufA[(64 + 2 * tid) * RS]     = make_float4(c0.x, c0.y, c1.x, c1.y);
      *(float4*)&bufA[(64 + 2 * tid + 1) * RS] = make_float4(c2.x, c2.y, c3.x, c3.y);
    }
    __syncthreads();

    // ---- phase A core: fz partials for 4 cols x 4 batches over 18 k ----
    float acc[4][4] = {};
#pragma unroll
    for (int i = 0; i < KSL; ++i) {
      float4 x0 = *(const float4*)&bufA[(kb + i) * RS];
#pragma unroll
      for (int m = 0; m < 4; ++m) {
        float wv = wA[i][m];
        acc[m][0] += wv * x0.x; acc[m][1] += wv * x0.y;
        acc[m][2] += wv * x0.z; acc[m][3] += wv * x0.w;
      }
    }

    // ---- reduce A (over g within wave) ----
#pragma unroll
    for (int m = 0; m < 4; ++m)
#pragma unroll
      for (int b = 0; b < 4; ++b) {
        acc[m][b] += __shfl_xor(acc[m][b], 8);
        acc[m][b] += __shfl_xor(acc[m][b], 16);
        acc[m][b] += __shfl_xor(acc[m][b], 32);
      }
    if (g == 0) {
#pragma unroll
      for (int m = 0; m < 4; ++m)
        *(float4*)&pA[(w * 32 + 4 * cq + m) * RS] =
            make_float4(acc[m][0], acc[m][1], acc[m][2], acc[m][3]);
    }
    __syncthreads();

    // ---- finalize A: sigmoid; fire packed fp16 f*x publishes; stash z ----
    if (tid < 128) {
      float s = pA[(0 * 32 + fcA) * RS + fb] + pA[(1 * 32 + fcA) * RS + fb] +
                pA[(2 * 32 + fcA) * RS + fb] + pA[(3 * 32 + fcA) * RS + fb] + biasA;
      float sig = 1.0f / (1.0f + __expf(-s));
      if (fcA < 16) {                  // wave 0 (uniform)
        float v = sig * bufA[(64 + 16 * cg + fcA) * RS + fb];
        float v1 = __shfl_xor(v, 1);   // neighbor batch
        if ((tid & 1) == 0)
          gpubh_nd(xfg + (size_t)(bg * H_ + 16 * cg + fcA) * 2 + (fb >> 1),
                   f2h2(v, v1));
      } else {                         // wave 1 (uniform)
        zreg = sig;
        xoldz = bufA[(64 + 16 * cg + (fcA - 16)) * RS + fb];
      }
    }

    // ---- y_t (LDS-only) covers part of the publish flight time ----
    float yp = 0.0f;
    {
#pragma unroll
      for (int i = 0; i < 8; ++i)
        yp += wy[i] * bufA[(64 + l + 64 * i) * RS + w];
      yp += __shfl_xor(yp, 1);  yp += __shfl_xor(yp, 2);
      yp += __shfl_xor(yp, 4);  yp += __shfl_xor(yp, 8);
      yp += __shfl_xor(yp, 16); yp += __shfl_xor(yp, 32);
    }

    // drain publishes -> sync -> bump (earliest possible)
    asm volatile("s_waitcnt vmcnt(0)" ::: "memory");
    __syncthreads();
    if (tid == 0) gaddu(ctrA, 1u);

    // out-store overlaps the barrier poll
    if (l == 0)
      out[((size_t)(bg * BPG + w) * T_ + t) * OUT_ + cg] = yp + by;

    if (!gbar_wait(ctrA, (unsigned)(NCG * (t + 1)), abort_w)) return;

    // ---- stage f*x into bufA ----
    {
      uint4 a;
      gload1(xfg + (size_t)bg * (H_ * 2) + tid * 4, a);
      float2 c0 = h2f2(a.x), c1 = h2f2(a.y), c2 = h2f2(a.z), c3 = h2f2(a.w);
      *(float4*)&bufA[(64 + 2 * tid) * RS]     = make_float4(c0.x, c0.y, c1.x, c1.y);
      *(float4*)&bufA[(64 + 2 * tid + 1) * RS] = make_float4(c2.x, c2.y, c3.x, c3.y);
    }
    __syncthreads();

    // ---- phase B core: r partials for 2 cols x 4 batches ----
    float acc2[2][4] = {};
#pragma unroll
    for (int i = 0; i < KSL; ++i) {
      float4 x0 = *(const float4*)&bufA[(kb + i) * RS];
#pragma unroll
      for (int m = 0; m < 2; ++m) {
        float wv = wB[i][m];
        acc2[m][0] += wv * x0.x; acc2[m][1] += wv * x0.y;
        acc2[m][2] += wv * x0.z; acc2[m][3] += wv * x0.w;
      }
    }
#pragma unroll
    for (int m = 0; m < 2; ++m)
#pragma unroll
      for (int b = 0; b < 4; ++b) {
        acc2[m][b] += __shfl_xor(acc2[m][b], 8);
        acc2[m][b] += __shfl_xor(acc2[m][b], 16);
        acc2[m][b] += __shfl_xor(acc2[m][b], 32);
      }
    if (g == 0) {
#pragma unroll
      for (int m = 0; m < 2; ++m)
        *(float4*)&pB[(w * 16 + 2 * cq + m) * RS] =
            make_float4(acc2[m][0], acc2[m][1], acc2[m][2], acc2[m][3]);
    }
    __syncthreads();

    // ---- finalize B: tanh -> rbuf ----
    if (tid < 64) {
      float s = pB[(0 * 16 + fcB) * RS + fb] + pB[(1 * 16 + fcB) * RS + fb] +
                pB[(2 * 16 + fcB) * RS + fb] + pB[(3 * 16 + fcB) * RS + fb] + biasB;
      float e = __expf(2.0f * s);
      rbuf[fcB * 4 + fb] = 1.0f - 2.0f / (1.0f + e);
    }
    __syncthreads();

    // ---- update: x_next = x + z*(r - x); fire packed fp16 publishes ----
    if (tid >= 64 && tid < 128) {      // wave 1 (uniform)
      int zr = fcA - 16;               // 0..15
      float r = rbuf[zr * 4 + fb];
      float xn = xoldz + zreg * (r - xoldz);
      float xn1 = __shfl_xor(xn, 1);
      if ((tid & 1) == 0)
        gpubh_nd(xnxt + (size_t)(bg * H_ + 16 * cg + zr) * 2 + (fb >> 1),
                 f2h2(xn, xn1));
    }

    // drain publishes -> sync -> bump; u-prefetch strictly AFTER the bump
    asm volatile("s_waitcnt vmcnt(0)" ::: "memory");
    __syncthreads();
    if (tid == 0) gaddu(ctrB, 1u);

    // ---- prefetch u_{t+1} into LDS while barrier-B resolves ----
    if (t + 1 < T_) {
      int k = tid & 63, b = tid >> 6;
      bufA[k * RS + b] = u[((size_t)(bg * BPG + b) * T_ + (t + 1)) * IN_ + k];
    }

    if (!gbar_wait(ctrB, (unsigned)(NCG * (t + 1)), abort_w)) return;
  }
}

extern "C" void kernel_launch(void* const* d_in, const int* in_sizes, int n_in,
                              void* d_out, int out_size, void* d_ws, size_t ws_size,
                              hipStream_t stream) {
  const float* u    = (const float*)d_in[0];
  const float* x0   = (const float*)d_in[1];
  const float* kfz  = (const float*)d_in[2];
  const float* bfz  = (const float*)d_in[3];
  const float* kr   = (const float*)d_in[4];
  const float* br   = (const float*)d_in[5];
  const float* wout = (const float*)d_in[6];
  const float* bout = (const float*)d_in[7];
  float* out = (float*)d_out;
  float* ws  = (float*)d_ws;

  hipLaunchKernelGGL(gru_init, dim3(64), dim3(256), 0, stream, ws, x0);
  hipLaunchKernelGGL(gru_main, dim3(NBG * NCG), dim3(NTHR), 0, stream,
                     u, kfz, bfz, kr, br, wout, bout, out, ws);
}

// Round 9
// 26298.209 us; speedup vs baseline: 1.4316x; 1.4316x over previous
//
#include <hip/hip_runtime.h>
#include <hip/hip_fp16.h>
#include <stdint.h>

// Problem dims
#define B_    64
#define T_    2048
#define IN_   64
#define H_    512
#define H2_   1024
#define OUT_  32
#define KTOT  576          // IN_ + H_

// Grid: 512 blocks = 16 batch-groups x 32 col-groups, 256 threads, 2 blocks/CU.
// bg = blockIdx>>5 so co-resident pairs (i, i+256) are DIFFERENT bgs ->
// independent sync domains anti-phase on one CU (TLP hides MALL RTs).
// LAUNCH BOUNDS LESSON (rounds 5+8): ANY min-occupancy request beyond
// (256,1) caps VGPR at 128 -> weight spill -> 5-10GB scratch traffic.
// (256,1) gives the allocator freedom (~150-200 VGPR); at <=256 VGPR the CU
// fits 8 waves = 2 blocks anyway (m69 capacity), so residency needs no hint.
#define NBG   16
#define NCG   32           // col-groups per bg (barrier fan-in, unchanged)
#define NTHR  256
#define BPG   4            // batches per group
#define KSL   18           // k per slice (32 slices x 18 = 576)
#define RS    12           // bufA row stride in floats (48B, 16B-aligned)

// ws layout (32-bit words)
// Counters: one u32 per (bg, phase), 4KB-strided (round-4 win). 32 counters.
// Slabs fp16: word = (bg*512 + col)*2 + pr, pr = batch-pair (b0=2pr, b1=2pr+1).
#define ABORT_IDX   0
#define CTR_OFF     1024
#define CTR_STRIDE  1024
#define NCTR        (NBG * 2)                       // 32
#define BUF_BASE    (CTR_OFF + NCTR * CTR_STRIDE)   // 33792
#define XSLABW      (NBG * H_ * 2)                  // 16384 words per slab

// ---- fp16 pack/unpack ----
__device__ __forceinline__ unsigned f2h2(float a, float b) {
  __half2 h = __floats2half2_rn(a, b);   // lo = a, hi = b
  unsigned r; __builtin_memcpy(&r, &h, 4); return r;
}
__device__ __forceinline__ float2 h2f2(unsigned u) {
  __half2 h; __builtin_memcpy(&h, &u, 4);
  return __half22float2(h);              // x = lo, y = hi
}

// ---- MALL-resident exchange primitives ----
// Publish packed fp16 pair: fire-and-forget 4B swap at the MALL (sc1).
// The drain (vmcnt 0) is issued explicitly later, after LDS-only work,
// and ALWAYS before the counter bump (round-6 lesson: nothing with VMEM
// between publish and bump; independent VMEM work goes after the bump).
__device__ __forceinline__ void gpubh_nd(unsigned* p, unsigned v) {
  asm volatile("global_atomic_swap %0, %1, off sc1"
               :: "v"(p), "v"(v) : "memory");
}
// Counter bump: fire-and-forget one-way add at the MALL.
__device__ __forceinline__ void gaddu(unsigned* p, unsigned v) {
  asm volatile("global_atomic_add %0, %1, off sc1"
               :: "v"(p), "v"(v) : "memory");
}
// Coherent 4B poll load (bypasses stale L1/L2, reads the MALL).
__device__ __forceinline__ unsigned gpollu(const unsigned* p) {
  unsigned v;
  asm volatile("global_load_dword %0, %1, off sc0 sc1\n\ts_waitcnt vmcnt(0)"
               : "=v"(v) : "v"(p) : "memory");
  return v;
}
// Consume: one MALL-coherent 16B load = 2 cols x 4 batches fp16.
__device__ __forceinline__ void gload1(const unsigned* p0, uint4& a) {
  asm volatile("global_load_dwordx4 %0, %1, off sc0 sc1\n\ts_waitcnt vmcnt(0)"
               : "=&v"(a) : "v"(p0) : "memory");
}

__global__ __launch_bounds__(256) void gru_init(float* ws, const float* __restrict__ x0) {
  int i = blockIdx.x * blockDim.x + threadIdx.x;
  int stride = gridDim.x * blockDim.x;
  unsigned* w = (unsigned*)ws;
  for (int k = i; k < BUF_BASE; k += stride) w[k] = 0u;   // abort + counters
  // xg0 slab (fp16): word p = (bg*512 + col)*2 + pr
  unsigned* xh = w + BUF_BASE;
  for (int p = i; p < XSLABW; p += stride) {
    int bg = p >> 10, col = (p >> 1) & (H_ - 1), pr = p & 1;
    int b0 = bg * BPG + 2 * pr;
    xh[p] = f2h2(x0[b0 * H_ + col], x0[(b0 + 1) * H_ + col]);
  }
}

// Wait: ONE lane polls ONE 4KB-isolated counter word until it reaches target.
__device__ __forceinline__ bool gbar_wait(unsigned* ctr, unsigned target,
                                          unsigned* abort_w) {
  __shared__ int s_ok;
  if (threadIdx.x == 0) {
    int ok = 1;
    int polls = 0;
    while (gpollu(ctr) < target) {
      __builtin_amdgcn_s_sleep(1);
      if ((++polls & 255) == 0) {
        if (__hip_atomic_load(abort_w, __ATOMIC_RELAXED, __HIP_MEMORY_SCOPE_AGENT) != 0u ||
            polls > 2000000) {
          __hip_atomic_store(abort_w, 1u, __ATOMIC_RELAXED, __HIP_MEMORY_SCOPE_AGENT);
          ok = 0;
          break;
        }
      }
    }
    s_ok = ok;
  }
  __syncthreads();
  __atomic_signal_fence(__ATOMIC_ACQUIRE);  // compiler reordering guard only
  return s_ok != 0;
}

__global__ __launch_bounds__(NTHR, 1) void gru_main(
    const float* __restrict__ u, const float* __restrict__ kfz,
    const float* __restrict__ bfz, const float* __restrict__ kr,
    const float* __restrict__ br, const float* __restrict__ wout,
    const float* __restrict__ bout, float* __restrict__ out, float* ws) {
  unsigned* wsu = (unsigned*)ws;
  unsigned* abort_w = wsu + ABORT_IDX;
  unsigned* xg0 = wsu + BUF_BASE;
  unsigned* xg1 = xg0 + XSLABW;
  unsigned* xfg = xg1 + XSLABW;

  const int bg  = blockIdx.x >> 5;   // batch group 0..15 (4 batches each)
  const int cg  = blockIdx.x & 31;   // column group 0..31
  const int tid = threadIdx.x;
  const int w   = tid >> 6;          // wave 0..3
  const int l   = tid & 63;
  const int cq  = l & 7;             // col-quad 0..7
  const int g   = l >> 3;            // in-wave k-slice 0..7
  const int kb  = (w * 8 + g) * KSL; // this thread's k base (18 k's)
  const int fcA = (tid >> 2) & 31;   // finalize-A col 0..31 (valid tid<128)
  const int fb  = tid & 3;           // finalize batch 0..3
  const int fcB = (tid >> 2) & 15;   // finalize-B col 0..15 (valid tid<64)

  unsigned* ctrA = wsu + CTR_OFF + (bg * 2 + 0) * CTR_STRIDE;
  unsigned* ctrB = wsu + CTR_OFF + (bg * 2 + 1) * CTR_STRIDE;

  __shared__ float bufA[KTOT * RS];  // [k][12]: u_t(k<64) | x or f*x (4 b)
  __shared__ float pA[4 * 32 * RS];
  __shared__ float pB[4 * 16 * RS];
  __shared__ float rbuf[16 * 4];

  // ---- one-time: weights into registers (~116 floats/thread) ----
  float wA[KSL][4];
#pragma unroll
  for (int i = 0; i < KSL; ++i)
#pragma unroll
    for (int m = 0; m < 4; ++m) {
      int c = 4 * cq + m;
      int gcol = (c < 16) ? (16 * cg + c) : (512 + 16 * cg + (c - 16));
      wA[i][m] = kfz[(size_t)(kb + i) * H2_ + gcol];
    }
  float wB[KSL][2];
#pragma unroll
  for (int i = 0; i < KSL; ++i)
#pragma unroll
    for (int m = 0; m < 2; ++m)
      wB[i][m] = kr[(size_t)(kb + i) * H_ + (16 * cg + 2 * cq + m)];
  float wy[8];                        // y: wave w = batch w, lane l = k-slice
#pragma unroll
  for (int i = 0; i < 8; ++i) wy[i] = wout[cg * H_ + (l + 64 * i)];
  const float by = bout[cg];
  const int fzc = (fcA < 16) ? (16 * cg + fcA) : (512 + 16 * cg + (fcA - 16));
  const float biasA = bfz[fzc];                  // index always in-bounds
  const float biasB = br[16 * cg + fcB];

  float zreg = 0.0f, xoldz = 0.0f;

  // u_t=0 into LDS rows 0..63 (later steps prefetched after bump-B)
  {
    int k = tid & 63, b = tid >> 6;
    bufA[k * RS + b] = u[((size_t)(bg * BPG + b) * T_) * IN_ + k];
  }

  for (int t = 0; t < T_; ++t) {
    unsigned* xcur = (t & 1) ? xg1 : xg0;
    unsigned* xnxt = (t & 1) ? xg0 : xg1;

    // ---- stage x into bufA: 1 dwordx4 = 2 cols x 4 batches ----
    {
      uint4 a;
      gload1(xcur + (size_t)bg * (H_ * 2) + tid * 4, a);
      float2 c0 = h2f2(a.x), c1 = h2f2(a.y), c2 = h2f2(a.z), c3 = h2f2(a.w);
      *(float4*)&bufA[(64 + 2 * tid) * RS]     = make_float4(c0.x, c0.y, c1.x, c1.y);
      *(float4*)&bufA[(64 + 2 * tid + 1) * RS] = make_float4(c2.x, c2.y, c3.x, c3.y);
    }
    __syncthreads();

    // ---- phase A core: fz partials for 4 cols x 4 batches over 18 k ----
    float acc[4][4] = {};
#pragma unroll
    for (int i = 0; i < KSL; ++i) {
      float4 x0 = *(const float4*)&bufA[(kb + i) * RS];
#pragma unroll
      for (int m = 0; m < 4; ++m) {
        float wv = wA[i][m];
        acc[m][0] += wv * x0.x; acc[m][1] += wv * x0.y;
        acc[m][2] += wv * x0.z; acc[m][3] += wv * x0.w;
      }
    }

    // ---- reduce A (over g within wave) ----
#pragma unroll
    for (int m = 0; m < 4; ++m)
#pragma unroll
      for (int b = 0; b < 4; ++b) {
        acc[m][b] += __shfl_xor(acc[m][b], 8);
        acc[m][b] += __shfl_xor(acc[m][b], 16);
        acc[m][b] += __shfl_xor(acc[m][b], 32);
      }
    if (g == 0) {
#pragma unroll
      for (int m = 0; m < 4; ++m)
        *(float4*)&pA[(w * 32 + 4 * cq + m) * RS] =
            make_float4(acc[m][0], acc[m][1], acc[m][2], acc[m][3]);
    }
    __syncthreads();

    // ---- finalize A: sigmoid; fire packed fp16 f*x publishes; stash z ----
    if (tid < 128) {
      float s = pA[(0 * 32 + fcA) * RS + fb] + pA[(1 * 32 + fcA) * RS + fb] +
                pA[(2 * 32 + fcA) * RS + fb] + pA[(3 * 32 + fcA) * RS + fb] + biasA;
      float sig = 1.0f / (1.0f + __expf(-s));
      if (fcA < 16) {                  // wave 0 (uniform)
        float v = sig * bufA[(64 + 16 * cg + fcA) * RS + fb];
        float v1 = __shfl_xor(v, 1);   // neighbor batch
        if ((tid & 1) == 0)
          gpubh_nd(xfg + (size_t)(bg * H_ + 16 * cg + fcA) * 2 + (fb >> 1),
                   f2h2(v, v1));
      } else {                         // wave 1 (uniform)
        zreg = sig;
        xoldz = bufA[(64 + 16 * cg + (fcA - 16)) * RS + fb];
      }
    }

    // ---- y_t (LDS-only) covers part of the publish flight time ----
    float yp = 0.0f;
    {
#pragma unroll
      for (int i = 0; i < 8; ++i)
        yp += wy[i] * bufA[(64 + l + 64 * i) * RS + w];
      yp += __shfl_xor(yp, 1);  yp += __shfl_xor(yp, 2);
      yp += __shfl_xor(yp, 4);  yp += __shfl_xor(yp, 8);
      yp += __shfl_xor(yp, 16); yp += __shfl_xor(yp, 32);
    }

    // drain publishes -> sync -> bump (earliest possible)
    asm volatile("s_waitcnt vmcnt(0)" ::: "memory");
    __syncthreads();
    if (tid == 0) gaddu(ctrA, 1u);

    // out-store overlaps the barrier poll
    if (l == 0)
      out[((size_t)(bg * BPG + w) * T_ + t) * OUT_ + cg] = yp + by;

    if (!gbar_wait(ctrA, (unsigned)(NCG * (t + 1)), abort_w)) return;

    // ---- stage f*x into bufA ----
    {
      uint4 a;
      gload1(xfg + (size_t)bg * (H_ * 2) + tid * 4, a);
      float2 c0 = h2f2(a.x), c1 = h2f2(a.y), c2 = h2f2(a.z), c3 = h2f2(a.w);
      *(float4*)&bufA[(64 + 2 * tid) * RS]     = make_float4(c0.x, c0.y, c1.x, c1.y);
      *(float4*)&bufA[(64 + 2 * tid + 1) * RS] = make_float4(c2.x, c2.y, c3.x, c3.y);
    }
    __syncthreads();

    // ---- phase B core: r partials for 2 cols x 4 batches ----
    float acc2[2][4] = {};
#pragma unroll
    for (int i = 0; i < KSL; ++i) {
      float4 x0 = *(const float4*)&bufA[(kb + i) * RS];
#pragma unroll
      for (int m = 0; m < 2; ++m) {
        float wv = wB[i][m];
        acc2[m][0] += wv * x0.x; acc2[m][1] += wv * x0.y;
        acc2[m][2] += wv * x0.z; acc2[m][3] += wv * x0.w;
      }
    }
#pragma unroll
    for (int m = 0; m < 2; ++m)
#pragma unroll
      for (int b = 0; b < 4; ++b) {
        acc2[m][b] += __shfl_xor(acc2[m][b], 8);
        acc2[m][b] += __shfl_xor(acc2[m][b], 16);
        acc2[m][b] += __shfl_xor(acc2[m][b], 32);
      }
    if (g == 0) {
#pragma unroll
      for (int m = 0; m < 2; ++m)
        *(float4*)&pB[(w * 16 + 2 * cq + m) * RS] =
            make_float4(acc2[m][0], acc2[m][1], acc2[m][2], acc2[m][3]);
    }
    __syncthreads();

    // ---- finalize B: tanh -> rbuf ----
    if (tid < 64) {
      float s = pB[(0 * 16 + fcB) * RS + fb] + pB[(1 * 16 + fcB) * RS + fb] +
                pB[(2 * 16 + fcB) * RS + fb] + pB[(3 * 16 + fcB) * RS + fb] + biasB;
      float e = __expf(2.0f * s);
      rbuf[fcB * 4 + fb] = 1.0f - 2.0f / (1.0f + e);
    }
    __syncthreads();

    // ---- update: x_next = x + z*(r - x); fire packed fp16 publishes ----
    if (tid >= 64 && tid < 128) {      // wave 1 (uniform)
      int zr = fcA - 16;               // 0..15
      float r = rbuf[zr * 4 + fb];
      float xn = xoldz + zreg * (r - xoldz);
      float xn1 = __shfl_xor(xn, 1);
      if ((tid & 1) == 0)
        gpubh_nd(xnxt + (size_t)(bg * H_ + 16 * cg + zr) * 2 + (fb >> 1),
                 f2h2(xn, xn1));
    }

    // drain publishes -> sync -> bump; u-prefetch strictly AFTER the bump
    asm volatile("s_waitcnt vmcnt(0)" ::: "memory");
    __syncthreads();
    if (tid == 0) gaddu(ctrB, 1u);

    // ---- prefetch u_{t+1} into LDS while barrier-B resolves ----
    if (t + 1 < T_) {
      int k = tid & 63, b = tid >> 6;
      bufA[k * RS + b] = u[((size_t)(bg * BPG + b) * T_ + (t + 1)) * IN_ + k];
    }

    if (!gbar_wait(ctrB, (unsigned)(NCG * (t + 1)), abort_w)) return;
  }
}

extern "C" void kernel_launch(void* const* d_in, const int* in_sizes, int n_in,
                              void* d_out, int out_size, void* d_ws, size_t ws_size,
                              hipStream_t stream) {
  const float* u    = (const float*)d_in[0];
  const float* x0   = (const float*)d_in[1];
  const float* kfz  = (const float*)d_in[2];
  const float* bfz  = (const float*)d_in[3];
  const float* kr   = (const float*)d_in[4];
  const float* br   = (const float*)d_in[5];
  const float* wout = (const float*)d_in[6];
  const float* bout = (const float*)d_in[7];
  float* out = (float*)d_out;
  float* ws  = (float*)d_ws;

  hipLaunchKernelGGL(gru_init, dim3(64), dim3(256), 0, stream, ws, x0);
  hipLaunchKernelGGL(gru_main, dim3(NBG * NCG), dim3(NTHR), 0, stream,
                     u, kfz, bfz, kr, br, wout, bout, out, ws);
}